// Round 5
// baseline (1388.229 us; speedup 1.0000x reference)
//
#include <hip/hip_runtime.h>
#include <hip/hip_bf16.h>
#include <math.h>

// TransformerBlock3D: B=8, C=128, S=32 (N=32768), HEADS=8 (dim_head=16), MLP=512
// Round 9: overlap x serial-length attack (R8 model confirmed: weight-stall fix
// gave 2.7x). Remaining: per-wave serial chain ~30-40K cyc with only 2 blocks/CU.
//  - k_mlp/k_attnproj: 64-n tiles (LDS 32KB/17KB) + launch_bounds(256,4)
//    -> 4 blocks/CU; staging loads explicitly batched (8 independent in flight).
//  - k_cov: staging batch-unrolled 8-wide (undo R6 over-de-unroll).
//  - k_greduce: unroll 8.
// Weight A-loads stay per-wave-sliced + batched (R8's fix; R7's trap avoided).
// Math: G=XX^T, attn=softmax(0.25*WqGWk^T), Mb=P.blockdiag(attn).Wv (bf16),
//       x1pre = Mb x + proj_b + x; x1 = LN1(x1pre); x2pre = x1 + b2 + W2 gelu(W1 x1 + b1).

#define N_SP 32768
typedef __hip_bfloat16 bf16;
static const size_t DS = (size_t)128 * N_SP;

typedef __attribute__((ext_vector_type(8))) short s8b;
typedef __attribute__((ext_vector_type(4))) float f4;

__device__ __forceinline__ ushort f2b(float f) {
    __hip_bfloat16 h = __float2bfloat16(f);
    return *reinterpret_cast<ushort*>(&h);
}
__device__ __forceinline__ float b2f(ushort u) {
    unsigned v = ((unsigned)u) << 16;
    float f;
    __builtin_memcpy(&f, &v, 4);
    return f;
}
__device__ __forceinline__ float gelu_f(float h) {
    float u = 1.5957691216057308f * h * fmaf(0.044715f, h * h, 1.0f);
    float e = __expf(u);
    return h * (1.0f - __builtin_amdgcn_rcpf(e + 1.0f));
}
// swizzled index for 128-col bf16 LDS tiles (c0 multiple of 8)
__device__ __forceinline__ int swz8(int n, int c0) {
    return n * 128 + (c0 ^ ((n & 15) << 3));
}
// swizzled index, c0 multiple of 4
__device__ __forceinline__ int swz4(int n, int c0) {
    return n * 128 + (((c0 & 0x78) ^ ((n & 15) << 3)) | (c0 & 4));
}

// ---------- tiny transpose ----------
__global__ __launch_bounds__(256) void k_transpose(const float* __restrict__ in,
                                                   float* __restrict__ out,
                                                   int R, int Ccols) {
    int idx = blockIdx.x * 256 + threadIdx.x;
    if (idx >= R * Ccols) return;
    int r = idx / Ccols, c = idx % Ccols;
    out[c * R + r] = in[idx];
}

// ---------- fp32 -> bf16 ----------
__global__ __launch_bounds__(256) void k_cvt(const float* __restrict__ in,
                                             ushort* __restrict__ out, int n) {
    int i = blockIdx.x * 256 + threadIdx.x;
    if (i < n) out[i] = f2b(in[i]);
}

// ---------- pack LN1 w/b (f32 [c][n]) -> bf16 pair (uint, [n][c]) ----------
__global__ __launch_bounds__(256) void k_packln(const float* __restrict__ w,
                                                const float* __restrict__ b,
                                                uint* __restrict__ out) {
    int tid = blockIdx.x * 256 + threadIdx.x;        // 4,194,304 elements
    int c = tid >> 15, n = tid & 32767;
    uint lo = f2b(w[tid]);
    uint hi = f2b(b[tid]);
    out[(size_t)n * 128 + c] = lo | (hi << 16);
}

// ---------- pack LN2 w/b (f32) -> bf16 pair (uint), same layout ----------
__global__ __launch_bounds__(256) void k_packflat(const float* __restrict__ w,
                                                  const float* __restrict__ b,
                                                  uint* __restrict__ out) {
    int tid = blockIdx.x * 256 + threadIdx.x;        // 4,194,304 elements
    uint lo = f2b(w[tid]);
    uint hi = f2b(b[tid]);
    out[tid] = lo | (hi << 16);
}

// ---------- covariance partials via MFMA: Gpart[b*128+kb] = X Xs^T over 256 n ----------
__global__ __launch_bounds__(256, 4) void k_cov(const float* __restrict__ x,
                                                float* __restrict__ Gpart) {
    __shared__ ushort xs[128 * 136];   // [c][n_local], pad 136 (16B-aligned rows)
    const int kb = blockIdx.x, b = blockIdx.y;
    const int t = threadIdx.x;
    const int wave = t >> 6, lane = t & 63, q = lane >> 4, r = lane & 15;
    f4 acc[8][2];
#pragma unroll
    for (int m = 0; m < 8; ++m) { acc[m][0] = (f4){0,0,0,0}; acc[m][1] = (f4){0,0,0,0}; }
    for (int ch = 0; ch < 2; ++ch) {
        const int nbase = kb * 256 + ch * 128;
        __syncthreads();
        {
            // float4-over-n staging, batched 8 loads in flight
            const int nq = t & 31, cr = t >> 5;      // 32 n-quads, 8 c-rows
            const float* xp = x + (size_t)b * DS + nbase + nq * 4;
#pragma unroll
            for (int half = 0; half < 2; ++half) {
                float4 xv[8];
#pragma unroll
                for (int cc = 0; cc < 8; ++cc)
                    xv[cc] = *(const float4*)(xp + (size_t)(cr * 16 + half * 8 + cc) * N_SP);
#pragma unroll
                for (int cc = 0; cc < 8; ++cc) {
                    int c = cr * 16 + half * 8 + cc;
                    ushort4 pk;
                    pk.x = f2b(xv[cc].x); pk.y = f2b(xv[cc].y);
                    pk.z = f2b(xv[cc].z); pk.w = f2b(xv[cc].w);
                    *(ushort4*)&xs[c * 136 + nq * 4] = pk;
                }
            }
        }
        __syncthreads();
        for (int kk = 0; kk < 4; ++kk) {
            const int c0 = kk * 32 + q * 8;
            s8b bj0 = *(const s8b*)&xs[(wave * 32 + r) * 136 + c0];
            s8b bj1 = *(const s8b*)&xs[(wave * 32 + 16 + r) * 136 + c0];
#pragma unroll
            for (int m = 0; m < 8; ++m) {
                s8b a = *(const s8b*)&xs[(m * 16 + r) * 136 + c0];
                acc[m][0] = __builtin_amdgcn_mfma_f32_16x16x32_bf16(a, bj0, acc[m][0], 0, 0, 0);
                acc[m][1] = __builtin_amdgcn_mfma_f32_16x16x32_bf16(a, bj1, acc[m][1], 0, 0, 0);
            }
        }
    }
    float* gp = Gpart + ((size_t)b * 128 + kb) * 16384;
#pragma unroll
    for (int n2 = 0; n2 < 2; ++n2)
#pragma unroll
        for (int m = 0; m < 8; ++m)
#pragma unroll
            for (int rg = 0; rg < 4; ++rg) {
                int i = m * 16 + q * 4 + rg;
                int j = wave * 32 + n2 * 16 + r;
                gp[i * 128 + j] = acc[m][n2][rg];
            }
}

__global__ __launch_bounds__(256) void k_greduce(const float* __restrict__ Gpart,
                                                 float* __restrict__ G) {
    int tid = blockIdx.x * 256 + threadIdx.x;
    int b = tid >> 14, ij = tid & 16383;
    float s = 0.f;
#pragma unroll 8
    for (int kb = 0; kb < 128; ++kb)
        s += Gpart[((size_t)b * 128 + kb) * 16384 + ij];
    G[tid] = s;
}

// ---------- gram + softmax ----------
__global__ __launch_bounds__(256) void k_gram_small(const float* __restrict__ G,
                                                    const float* __restrict__ qkv_w,
                                                    float* __restrict__ attn) {
    __shared__ float t1[16 * 132];
    __shared__ float sg[16 * 16];
    const int bh = blockIdx.x;
    const int b = bh >> 3, h = bh & 7;
    const int t = threadIdx.x;
    {
        const int i = t >> 4, c20 = (t & 15) * 8;
        const float* wq = qkv_w + (size_t)(h * 16 + i) * 128;
        const float* Gb = G + (size_t)b * 16384;
        float a[8];
#pragma unroll
        for (int k = 0; k < 8; ++k) a[k] = 0.f;
        for (int c = 0; c < 128; ++c) {
            float w = wq[c];
            const float* grow = Gb + c * 128 + c20;
#pragma unroll
            for (int k = 0; k < 8; ++k) a[k] = fmaf(w, grow[k], a[k]);
        }
#pragma unroll
        for (int k = 0; k < 8; ++k) t1[i * 132 + c20 + k] = a[k];
    }
    __syncthreads();
    {
        const int i = t >> 4, j = t & 15;
        const float* wk = qkv_w + (size_t)(128 + h * 16 + j) * 128;
        float s = 0.f;
        for (int c2 = 0; c2 < 128; ++c2) s = fmaf(t1[i * 132 + c2], wk[c2], s);
        sg[i * 16 + j] = s * 0.25f;
    }
    __syncthreads();
    if (t < 16) {
        float mx = -1e30f;
#pragma unroll
        for (int j = 0; j < 16; ++j) mx = fmaxf(mx, sg[t * 16 + j]);
        float e[16], sum = 0.f;
#pragma unroll
        for (int j = 0; j < 16; ++j) { e[j] = expf(sg[t * 16 + j] - mx); sum += e[j]; }
        float inv = 1.0f / sum;
#pragma unroll
        for (int j = 0; j < 16; ++j)
            attn[((size_t)bh * 16 + t) * 16 + j] = e[j] * inv;
    }
}

// ---------- fold: Mbb[b][o][c] = bf16( (P . blockdiag(attn) . Wv)[o][c] ) ----------
__global__ __launch_bounds__(256, 2) void k_mfold(const float* __restrict__ attn,
                                                  const float* __restrict__ qkv_w,
                                                  const float* __restrict__ PT,
                                                  ushort* __restrict__ Mbb) {
    __shared__ float t2[128 * 128];
    const int b = blockIdx.x, t = threadIdx.x;
    {
        const int hi = t >> 1, c0 = (t & 1) * 64;
        const int h = hi >> 4;
        const float* at = attn + ((size_t)b * 128 + hi) * 16;
        float a[16];
#pragma unroll
        for (int j = 0; j < 16; ++j) a[j] = at[j];
        float sc[64];
#pragma unroll
        for (int c = 0; c < 64; ++c) sc[c] = 0.f;
        for (int j = 0; j < 16; ++j) {
            const float* wv = qkv_w + (size_t)(256 + h * 16 + j) * 128 + c0;
            float aj = a[j];
#pragma unroll
            for (int c = 0; c < 64; ++c) sc[c] = fmaf(aj, wv[c], sc[c]);
        }
#pragma unroll
        for (int c = 0; c < 64; ++c) t2[hi * 128 + c0 + c] = sc[c];
    }
    __syncthreads();
    const int c = t & 127, half = t >> 7;
    float acc[128];
#pragma unroll
    for (int o = 0; o < 128; ++o) acc[o] = 0.f;
    for (int ci = half * 64; ci < half * 64 + 64; ++ci) {
        float s = t2[ci * 128 + c];
        const float* pt = PT + ci * 128;
#pragma unroll
        for (int o = 0; o < 128; ++o) acc[o] = fmaf(pt[o], s, acc[o]);
    }
    __syncthreads();
    if (half) {
#pragma unroll
        for (int o = 0; o < 128; ++o) t2[c * 128 + o] = acc[o];
    }
    __syncthreads();
    if (!half) {
        ushort* m = Mbb + (size_t)b * 16384;
#pragma unroll
        for (int o = 0; o < 128; ++o)
            m[(size_t)o * 128 + c] = f2b(acc[o] + t2[c * 128 + o]);
    }
}

// ---------- attnproj: x1pre = Mb x + proj_b + x -> x1T[b][n][c], LN1 stats ----------
// 64-n tile; wave owns 32 output rows x 64 n. Staging: 8 batched float4-over-n.
__global__ __launch_bounds__(256, 4) void k_attnproj(const float* __restrict__ x,
                                                     const ushort* __restrict__ Mbb,
                                                     const float* __restrict__ proj_b,
                                                     float* __restrict__ x1T,
                                                     float* __restrict__ st) {
    __shared__ ushort xT[64 * 136];    // [n][c] bf16, pad 136
    const int b = blockIdx.y;
    const int n0 = blockIdx.x * 64;
    const int t = threadIdx.x;
    const int wave = t >> 6, lane = t & 63, q = lane >> 4, r = lane & 15;
    {
        const int nq = (t & 15) * 4;     // n-quad start (16 quads cover 64 n)
        const int cr = t >> 4;           // 16 c-rows; 8 c per thread (stride 16)
        const float* xb = x + (size_t)b * DS + n0 + nq;
        float4 xv[8];
#pragma unroll
        for (int g = 0; g < 8; ++g)
            xv[g] = *(const float4*)(xb + (size_t)(cr + g * 16) * N_SP);
#pragma unroll
        for (int g = 0; g < 8; ++g) {
            int c = cr + g * 16;
            xT[(nq + 0) * 136 + c] = f2b(xv[g].x);
            xT[(nq + 1) * 136 + c] = f2b(xv[g].y);
            xT[(nq + 2) * 136 + c] = f2b(xv[g].z);
            xT[(nq + 3) * 136 + c] = f2b(xv[g].w);
        }
    }
    const int orow = wave * 32 + r;
    // prefetch the wave's Mb slice: 8 independent loads (overlaps barrier)
    s8b a[8];
    {
        const ushort* mp = Mbb + (size_t)b * 16384 + (size_t)orow * 128 + q * 8;
#pragma unroll
        for (int m = 0; m < 2; ++m)
#pragma unroll
            for (int kk = 0; kk < 4; ++kk)
                a[m * 4 + kk] = *(const s8b*)(mp + m * 16 * 128 + kk * 32);
    }
    __syncthreads();
    f4 acc[2][4];
#pragma unroll
    for (int m = 0; m < 2; ++m)
#pragma unroll
        for (int j = 0; j < 4; ++j) acc[m][j] = (f4){0,0,0,0};
#pragma unroll
    for (int kk = 0; kk < 4; ++kk) {
        const int c0 = kk * 32 + q * 8;
#pragma unroll
        for (int j = 0; j < 4; ++j) {
            s8b bx = *(const s8b*)&xT[(j * 16 + r) * 136 + c0];
            acc[0][j] = __builtin_amdgcn_mfma_f32_16x16x32_bf16(a[kk],     bx, acc[0][j], 0, 0, 0);
            acc[1][j] = __builtin_amdgcn_mfma_f32_16x16x32_bf16(a[4 + kk], bx, acc[1][j], 0, 0, 0);
        }
    }
    float s = 0.f, sq = 0.f;
    float4 pbq0 = *(const float4*)&proj_b[wave * 32 + q * 4];
    float4 pbq1 = *(const float4*)&proj_b[wave * 32 + 16 + q * 4];
#pragma unroll
    for (int m = 0; m < 2; ++m) {
        const int o0 = wave * 32 + m * 16 + q * 4;
        const float4 pb = m ? pbq1 : pbq0;
#pragma unroll
        for (int j = 0; j < 4; ++j) {
            const int nn = j * 16 + r;
            ushort4 xr = *(const ushort4*)&xT[nn * 136 + o0];
            float v0 = acc[m][j][0] + pb.x + b2f(xr.x);
            float v1 = acc[m][j][1] + pb.y + b2f(xr.y);
            float v2 = acc[m][j][2] + pb.z + b2f(xr.z);
            float v3 = acc[m][j][3] + pb.w + b2f(xr.w);
            float4 ov; ov.x = v0; ov.y = v1; ov.z = v2; ov.w = v3;
            *(float4*)(x1T + (size_t)b * DS + (size_t)(n0 + nn) * 128 + o0) = ov;
            s += (v0 + v1) + (v2 + v3);
            sq = fmaf(v0, v0, sq); sq = fmaf(v1, v1, sq);
            sq = fmaf(v2, v2, sq); sq = fmaf(v3, v3, sq);
        }
    }
#pragma unroll
    for (int off = 32; off > 0; off >>= 1) {
        s += __shfl_down(s, off, 64);
        sq += __shfl_down(sq, off, 64);
    }
    if (lane == 0) {
        atomicAdd(&st[0 + b], s);
        atomicAdd(&st[8 + b], sq);
    }
}

__global__ void k_finalize(float* st, int off) {
    int b = threadIdx.x;
    if (b < 8) {
        const float invn = 1.0f / 4194304.0f;
        float mu = st[off + b] * invn;
        float var = st[off + 8 + b] * invn - mu * mu;
        st[off + 16 + b] = mu;
        st[off + 24 + b] = rsqrtf(var + 1e-5f);
    }
}

// ---------- LN2 apply with packed bf16 params ----------
__global__ __launch_bounds__(256) void k_lnapply(const float* __restrict__ in,
                                                 const uint* __restrict__ lnwb,
                                                 const float* __restrict__ st, int off,
                                                 float* __restrict__ out) {
    size_t i4 = (size_t)blockIdx.x * 256 + threadIdx.x;
    int b = (int)(i4 >> 20);
    size_t cn = i4 * 4 - (size_t)b * 4194304;
    float mu = st[off + 16 + b], rs = st[off + 24 + b];
    const float4 xv = *(const float4*)(in + (size_t)b * DS + cn);
    const uint4 wv = *(const uint4*)(lnwb + cn);
    float4 o;
    o.x = fmaf((xv.x - mu) * rs, b2f((ushort)(wv.x & 0xffffu)), b2f((ushort)(wv.x >> 16)));
    o.y = fmaf((xv.y - mu) * rs, b2f((ushort)(wv.y & 0xffffu)), b2f((ushort)(wv.y >> 16)));
    o.z = fmaf((xv.z - mu) * rs, b2f((ushort)(wv.z & 0xffffu)), b2f((ushort)(wv.z >> 16)));
    o.w = fmaf((xv.w - mu) * rs, b2f((ushort)(wv.w & 0xffffu)), b2f((ushort)(wv.w >> 16)));
    *(float4*)(out + (size_t)b * DS + cn) = o;
}

// ---------- fused LN1-apply + MLP + residual + LN2 stats, 64-n tile ----------
// Wave w owns 32 output rows x 64 n per phase. Weight A-loads: 8/phase/wave,
// prefetched and overlapped across phases. Staging: 2 batches of 8 loads.
__global__ __launch_bounds__(256, 4) void k_mlp(const float* __restrict__ x1T,
                                                float* __restrict__ xout,
                                                const ushort* __restrict__ w1b,
                                                const float* __restrict__ b1v,
                                                const ushort* __restrict__ w2b,
                                                const float* __restrict__ b2v,
                                                const uint* __restrict__ lnwbT,
                                                float* __restrict__ st) {
    __shared__ ushort xT[64 * 128];    // swizzled, x1 = LN1(x1pre) bf16
    __shared__ ushort hT[64 * 128];    // swizzled, gelu os-slice [n][hr] bf16
    const int b = blockIdx.y;
    const int n0 = blockIdx.x * 64;
    const int t = threadIdx.x;
    const int wave = t >> 6, lane = t & 63, q = lane >> 4, r = lane & 15;
    const float mu = st[16 + b], rs = st[24 + b];
    {
        // coalesced staging: 32 lanes x 16B = 512B lines; 2 batches of 4 rows
        const int cq = (t & 31) * 4;
        const int rb = t >> 5;
        const float* xb = x1T + (size_t)b * DS + (size_t)n0 * 128;
        const uint*  wb = lnwbT + (size_t)n0 * 128;
#pragma unroll
        for (int gb = 0; gb < 2; ++gb) {
            float4 xv[4]; uint4 wv[4];
#pragma unroll
            for (int u = 0; u < 4; ++u) {
                int nn = (gb * 4 + u) * 8 + rb;
                xv[u] = *(const float4*)(xb + (size_t)nn * 128 + cq);
                wv[u] = *(const uint4*)(wb + (size_t)nn * 128 + cq);
            }
#pragma unroll
            for (int u = 0; u < 4; ++u) {
                int nn = (gb * 4 + u) * 8 + rb;
                ushort4 pk;
                pk.x = f2b(fmaf((xv[u].x - mu) * rs, b2f((ushort)(wv[u].x & 0xffffu)), b2f((ushort)(wv[u].x >> 16))));
                pk.y = f2b(fmaf((xv[u].y - mu) * rs, b2f((ushort)(wv[u].y & 0xffffu)), b2f((ushort)(wv[u].y >> 16))));
                pk.z = f2b(fmaf((xv[u].z - mu) * rs, b2f((ushort)(wv[u].z & 0xffffu)), b2f((ushort)(wv[u].z >> 16))));
                pk.w = f2b(fmaf((xv[u].w - mu) * rs, b2f((ushort)(wv[u].w & 0xffffu)), b2f((ushort)(wv[u].w >> 16))));
                *(ushort4*)&xT[swz4(nn, cq)] = pk;
            }
        }
    }
    const int orow = wave * 32 + r;
    // prefetch GEMM1 A-slice for os=0 (8 independent loads), overlaps barrier
    s8b a1[8];
    {
        const ushort* w1p = w1b + (size_t)orow * 128 + q * 8;
#pragma unroll
        for (int m = 0; m < 2; ++m)
#pragma unroll
            for (int kk = 0; kk < 4; ++kk)
                a1[m * 4 + kk] = *(const s8b*)(w1p + m * 16 * 128 + kk * 32);
    }
    __syncthreads();
    f4 acc2[2][4];
#pragma unroll
    for (int m = 0; m < 2; ++m)
#pragma unroll
        for (int j = 0; j < 4; ++j) acc2[m][j] = (f4){0,0,0,0};

    for (int os = 0; os < 4; ++os) {
        // ---- GEMM1: h[os-slice rows owned by wave] = W1 x1 ----
        f4 acc1[2][4];
#pragma unroll
        for (int m = 0; m < 2; ++m)
#pragma unroll
            for (int j = 0; j < 4; ++j) acc1[m][j] = (f4){0,0,0,0};
#pragma unroll
        for (int kk = 0; kk < 4; ++kk) {
            const int c0 = kk * 32 + q * 8;
#pragma unroll
            for (int j = 0; j < 4; ++j) {
                s8b bx = *(const s8b*)&xT[swz8(j * 16 + r, c0)];
                acc1[0][j] = __builtin_amdgcn_mfma_f32_16x16x32_bf16(a1[kk],     bx, acc1[0][j], 0, 0, 0);
                acc1[1][j] = __builtin_amdgcn_mfma_f32_16x16x32_bf16(a1[4 + kk], bx, acc1[1][j], 0, 0, 0);
            }
        }
        // prefetch GEMM2 A-slice for this os (independent of hT)
        s8b a2[8];
        {
            const ushort* w2p = w2b + (size_t)orow * 512 + os * 128 + q * 8;
#pragma unroll
            for (int m = 0; m < 2; ++m)
#pragma unroll
                for (int kk = 0; kk < 4; ++kk)
                    a2[m * 4 + kk] = *(const s8b*)(w2p + m * 16 * 512 + kk * 32);
        }
        float4 b1q0 = *(const float4*)&b1v[os * 128 + wave * 32 + q * 4];
        float4 b1q1 = *(const float4*)&b1v[os * 128 + wave * 32 + 16 + q * 4];
        // ---- gelu -> hT (cross-wave) ----
#pragma unroll
        for (int m = 0; m < 2; ++m) {
            const int hr0 = wave * 32 + m * 16 + q * 4;
            const float4 bq = m ? b1q1 : b1q0;
#pragma unroll
            for (int j = 0; j < 4; ++j) {
                ushort4 pk;
                pk.x = f2b(gelu_f(acc1[m][j][0] + bq.x));
                pk.y = f2b(gelu_f(acc1[m][j][1] + bq.y));
                pk.z = f2b(gelu_f(acc1[m][j][2] + bq.z));
                pk.w = f2b(gelu_f(acc1[m][j][3] + bq.w));
                *(ushort4*)&hT[swz4(j * 16 + r, hr0)] = pk;
            }
        }
        __syncthreads();   // hT complete across waves
        // ---- GEMM2: acc2 += W2[:, os-slice] h ----
#pragma unroll
        for (int kk = 0; kk < 4; ++kk) {
            const int c0 = kk * 32 + q * 8;
#pragma unroll
            for (int j = 0; j < 4; ++j) {
                s8b hx = *(const s8b*)&hT[swz8(j * 16 + r, c0)];
                acc2[0][j] = __builtin_amdgcn_mfma_f32_16x16x32_bf16(a2[kk],     hx, acc2[0][j], 0, 0, 0);
                acc2[1][j] = __builtin_amdgcn_mfma_f32_16x16x32_bf16(a2[4 + kk], hx, acc2[1][j], 0, 0, 0);
            }
        }
        // prefetch next os's GEMM1 A-slice (overlaps barrier drain)
        if (os < 3) {
            const ushort* w1p = w1b + (size_t)((os + 1) * 128 + orow) * 128 + q * 8;
#pragma unroll
            for (int m = 0; m < 2; ++m)
#pragma unroll
                for (int kk = 0; kk < 4; ++kk)
                    a1[m * 4 + kk] = *(const s8b*)(w1p + m * 16 * 128 + kk * 32);
        }
        __syncthreads();   // hT consumed; safe to overwrite next os
    }
    // ---- epilogue: residual + b2, strided store to out[c][n], LN2 stats ----
    float s = 0.f, sq = 0.f;
    float4 b2q0 = *(const float4*)&b2v[wave * 32 + q * 4];
    float4 b2q1 = *(const float4*)&b2v[wave * 32 + 16 + q * 4];
#pragma unroll
    for (int m = 0; m < 2; ++m) {
        const int o0 = wave * 32 + m * 16 + q * 4;
        const float4 bq = m ? b2q1 : b2q0;
#pragma unroll
        for (int j = 0; j < 4; ++j) {
            const int nn = j * 16 + r;
            ushort4 xr = *(const ushort4*)&xT[swz4(nn, o0)];
            float v0 = acc2[m][j][0] + bq.x + b2f(xr.x);
            float v1 = acc2[m][j][1] + bq.y + b2f(xr.y);
            float v2 = acc2[m][j][2] + bq.z + b2f(xr.z);
            float v3 = acc2[m][j][3] + bq.w + b2f(xr.w);
            float* op = xout + (size_t)b * DS + n0 + nn;
            op[(size_t)(o0 + 0) * N_SP] = v0;
            op[(size_t)(o0 + 1) * N_SP] = v1;
            op[(size_t)(o0 + 2) * N_SP] = v2;
            op[(size_t)(o0 + 3) * N_SP] = v3;
            s += (v0 + v1) + (v2 + v3);
            sq = fmaf(v0, v0, sq); sq = fmaf(v1, v1, sq);
            sq = fmaf(v2, v2, sq); sq = fmaf(v3, v3, sq);
        }
    }
#pragma unroll
    for (int off = 32; off > 0; off >>= 1) {
        s += __shfl_down(s, off, 64);
        sq += __shfl_down(sq, off, 64);
    }
    if (lane == 0) {
        atomicAdd(&st[32 + b], s);
        atomicAdd(&st[40 + b], sq);
    }
}

extern "C" void kernel_launch(void* const* d_in, const int* in_sizes, int n_in,
                              void* d_out, int out_size, void* d_ws, size_t ws_size,
                              hipStream_t stream) {
    const float* x      = (const float*)d_in[0];
    const float* qkv_w  = (const float*)d_in[1];
    const float* proj_w = (const float*)d_in[2];
    const float* proj_b = (const float*)d_in[3];
    const float* ln1_w  = (const float*)d_in[4];
    const float* ln1_b  = (const float*)d_in[5];
    const float* ln2_w  = (const float*)d_in[6];
    const float* ln2_b  = (const float*)d_in[7];
    const float* mlp_w1 = (const float*)d_in[8];
    const float* mlp_b1 = (const float*)d_in[9];
    const float* mlp_w2 = (const float*)d_in[10];
    const float* mlp_b2 = (const float*)d_in[11];
    float* out = (float*)d_out;

    char* wsb = (char*)d_ws;
    // small persistent region
    float*  st    = (float*)wsb;                      // 256 B
    float*  attn  = (float*)(wsb + 256);              // 65,536
    float*  PT    = (float*)(wsb + 65792);            // 65,536
    ushort* Mbb   = (ushort*)(wsb + 131328);          // 262,144
    ushort* w1b   = (ushort*)(wsb + 393472);          // 131,072
    ushort* w2b   = (ushort*)(wsb + 524544);          // 131,072
    float*  G     = (float*)(wsb + 655616);           // 524,288
    uint*   lnwbT = (uint*)(wsb + 1179904);           // 16,777,216
    // big dual-use region (stream-ordered lifetimes):
    //   Gpart (67MB, dead after k_greduce) -> x1T (134MB, dead after k_mlp)
    //   -> lnwb2 (16MB, for k_lnapply)
    float*  Gpart = (float*)(wsb + 18874368);         // 67,108,864
    float*  x1T   = (float*)(wsb + 18874368);         // 134,217,728
    uint*   lnwb2 = (uint*)(wsb + 18874368);          // 16,777,216

    hipMemsetAsync(st, 0, 64 * sizeof(float), stream);

    k_transpose<<<64, 256, 0, stream>>>(proj_w, PT, 128, 128);
    k_cvt<<<256, 256, 0, stream>>>(mlp_w1, w1b, 65536);
    k_cvt<<<256, 256, 0, stream>>>(mlp_w2, w2b, 65536);
    k_packln<<<16384, 256, 0, stream>>>(ln1_w, ln1_b, lnwbT);

    k_cov<<<dim3(128, 8), 256, 0, stream>>>(x, Gpart);
    k_greduce<<<512, 256, 0, stream>>>(Gpart, G);
    k_gram_small<<<64, 256, 0, stream>>>(G, qkv_w, attn);
    k_mfold<<<8, 256, 0, stream>>>(attn, qkv_w, PT, Mbb);

    k_attnproj<<<dim3(512, 8), 256, 0, stream>>>(x, Mbb, proj_b, x1T, st);
    k_finalize<<<1, 64, 0, stream>>>(st, 0);
    k_mlp<<<dim3(512, 8), 256, 0, stream>>>(x1T, out, w1b, mlp_b1, w2b, mlp_b2,
                                            lnwbT, st);
    // x1T dead; pack LN2 params into the same region for the final apply
    k_packflat<<<16384, 256, 0, stream>>>(ln2_w, ln2_b, lnwb2);
    k_finalize<<<1, 64, 0, stream>>>(st, 32);
    k_lnapply<<<32768, 256, 0, stream>>>(out, lnwb2, st, 32, out);
}

// Round 6
// 970.630 us; speedup vs baseline: 1.4302x; 1.4302x over previous
//
#include <hip/hip_runtime.h>
#include <hip/hip_bf16.h>
#include <math.h>

// TransformerBlock3D: B=8, C=128, S=32 (N=32768), HEADS=8 (dim_head=16), MLP=512
// Round 10: revert to R8 tile geometry (128-n, proven 275us k_mlp) after R9's
// 64-n regression (weight traffic doubled: FETCH 121->180MB, write amp
// 131->218MB; dur x MfmaUtil invariant ~2780 again). Two targeted fixes:
//  - staging loads explicitly batched (12-16 in flight) in k_mlp/k_attnproj
//    (same batching lever that won R8, applied to activation staging).
//  - x1pre stored bf16 [n][c] (67MB vs 134MB): LN1 stats stay f32 (attnproj
//    accumulators); xT was already bf16, so rounding moves before the affine
//    apply -> same error order.
// Math: G=XX^T, attn=softmax(0.25*WqGWk^T), Mb=P.blockdiag(attn).Wv (bf16),
//       x1pre = Mb x + proj_b + x; x1 = LN1(x1pre); x2pre = x1 + b2 + W2 gelu(W1 x1 + b1).

#define N_SP 32768
typedef __hip_bfloat16 bf16;
static const size_t DS = (size_t)128 * N_SP;

typedef __attribute__((ext_vector_type(8))) short s8b;
typedef __attribute__((ext_vector_type(4))) float f4;

__device__ __forceinline__ ushort f2b(float f) {
    __hip_bfloat16 h = __float2bfloat16(f);
    return *reinterpret_cast<ushort*>(&h);
}
__device__ __forceinline__ float b2f(ushort u) {
    unsigned v = ((unsigned)u) << 16;
    float f;
    __builtin_memcpy(&f, &v, 4);
    return f;
}
__device__ __forceinline__ float gelu_f(float h) {
    float u = 1.5957691216057308f * h * fmaf(0.044715f, h * h, 1.0f);
    float e = __expf(u);
    return h * (1.0f - __builtin_amdgcn_rcpf(e + 1.0f));
}
// swizzled index for 128-col bf16 LDS tiles (c0 multiple of 8)
__device__ __forceinline__ int swz8(int n, int c0) {
    return n * 128 + (c0 ^ ((n & 15) << 3));
}
// swizzled index, c0 multiple of 4
__device__ __forceinline__ int swz4(int n, int c0) {
    return n * 128 + (((c0 & 0x78) ^ ((n & 15) << 3)) | (c0 & 4));
}

// ---------- tiny transpose ----------
__global__ __launch_bounds__(256) void k_transpose(const float* __restrict__ in,
                                                   float* __restrict__ out,
                                                   int R, int Ccols) {
    int idx = blockIdx.x * 256 + threadIdx.x;
    if (idx >= R * Ccols) return;
    int r = idx / Ccols, c = idx % Ccols;
    out[c * R + r] = in[idx];
}

// ---------- fp32 -> bf16 ----------
__global__ __launch_bounds__(256) void k_cvt(const float* __restrict__ in,
                                             ushort* __restrict__ out, int n) {
    int i = blockIdx.x * 256 + threadIdx.x;
    if (i < n) out[i] = f2b(in[i]);
}

// ---------- pack LN1 w/b (f32 [c][n]) -> bf16 pair (uint, [n][c]) ----------
__global__ __launch_bounds__(256) void k_packln(const float* __restrict__ w,
                                                const float* __restrict__ b,
                                                uint* __restrict__ out) {
    int tid = blockIdx.x * 256 + threadIdx.x;        // 4,194,304 elements
    int c = tid >> 15, n = tid & 32767;
    uint lo = f2b(w[tid]);
    uint hi = f2b(b[tid]);
    out[(size_t)n * 128 + c] = lo | (hi << 16);
}

// ---------- pack LN2 w/b (f32) -> bf16 pair (uint), same layout ----------
__global__ __launch_bounds__(256) void k_packflat(const float* __restrict__ w,
                                                  const float* __restrict__ b,
                                                  uint* __restrict__ out) {
    int tid = blockIdx.x * 256 + threadIdx.x;        // 4,194,304 elements
    uint lo = f2b(w[tid]);
    uint hi = f2b(b[tid]);
    out[tid] = lo | (hi << 16);
}

// ---------- covariance partials via MFMA: Gpart[b*128+kb] = X Xs^T over 256 n ----------
__global__ __launch_bounds__(256, 4) void k_cov(const float* __restrict__ x,
                                                float* __restrict__ Gpart) {
    __shared__ ushort xs[128 * 136];   // [c][n_local], pad 136 (16B-aligned rows)
    const int kb = blockIdx.x, b = blockIdx.y;
    const int t = threadIdx.x;
    const int wave = t >> 6, lane = t & 63, q = lane >> 4, r = lane & 15;
    f4 acc[8][2];
#pragma unroll
    for (int m = 0; m < 8; ++m) { acc[m][0] = (f4){0,0,0,0}; acc[m][1] = (f4){0,0,0,0}; }
    for (int ch = 0; ch < 2; ++ch) {
        const int nbase = kb * 256 + ch * 128;
        __syncthreads();
        {
            // float4-over-n staging, batched 8 loads in flight
            const int nq = t & 31, cr = t >> 5;      // 32 n-quads, 8 c-rows
            const float* xp = x + (size_t)b * DS + nbase + nq * 4;
#pragma unroll
            for (int half = 0; half < 2; ++half) {
                float4 xv[8];
#pragma unroll
                for (int cc = 0; cc < 8; ++cc)
                    xv[cc] = *(const float4*)(xp + (size_t)(cr * 16 + half * 8 + cc) * N_SP);
#pragma unroll
                for (int cc = 0; cc < 8; ++cc) {
                    int c = cr * 16 + half * 8 + cc;
                    ushort4 pk;
                    pk.x = f2b(xv[cc].x); pk.y = f2b(xv[cc].y);
                    pk.z = f2b(xv[cc].z); pk.w = f2b(xv[cc].w);
                    *(ushort4*)&xs[c * 136 + nq * 4] = pk;
                }
            }
        }
        __syncthreads();
        for (int kk = 0; kk < 4; ++kk) {
            const int c0 = kk * 32 + q * 8;
            s8b bj0 = *(const s8b*)&xs[(wave * 32 + r) * 136 + c0];
            s8b bj1 = *(const s8b*)&xs[(wave * 32 + 16 + r) * 136 + c0];
#pragma unroll
            for (int m = 0; m < 8; ++m) {
                s8b a = *(const s8b*)&xs[(m * 16 + r) * 136 + c0];
                acc[m][0] = __builtin_amdgcn_mfma_f32_16x16x32_bf16(a, bj0, acc[m][0], 0, 0, 0);
                acc[m][1] = __builtin_amdgcn_mfma_f32_16x16x32_bf16(a, bj1, acc[m][1], 0, 0, 0);
            }
        }
    }
    float* gp = Gpart + ((size_t)b * 128 + kb) * 16384;
#pragma unroll
    for (int n2 = 0; n2 < 2; ++n2)
#pragma unroll
        for (int m = 0; m < 8; ++m)
#pragma unroll
            for (int rg = 0; rg < 4; ++rg) {
                int i = m * 16 + q * 4 + rg;
                int j = wave * 32 + n2 * 16 + r;
                gp[i * 128 + j] = acc[m][n2][rg];
            }
}

__global__ __launch_bounds__(256) void k_greduce(const float* __restrict__ Gpart,
                                                 float* __restrict__ G) {
    int tid = blockIdx.x * 256 + threadIdx.x;
    int b = tid >> 14, ij = tid & 16383;
    float s = 0.f;
#pragma unroll 8
    for (int kb = 0; kb < 128; ++kb)
        s += Gpart[((size_t)b * 128 + kb) * 16384 + ij];
    G[tid] = s;
}

// ---------- gram + softmax ----------
__global__ __launch_bounds__(256) void k_gram_small(const float* __restrict__ G,
                                                    const float* __restrict__ qkv_w,
                                                    float* __restrict__ attn) {
    __shared__ float t1[16 * 132];
    __shared__ float sg[16 * 16];
    const int bh = blockIdx.x;
    const int b = bh >> 3, h = bh & 7;
    const int t = threadIdx.x;
    {
        const int i = t >> 4, c20 = (t & 15) * 8;
        const float* wq = qkv_w + (size_t)(h * 16 + i) * 128;
        const float* Gb = G + (size_t)b * 16384;
        float a[8];
#pragma unroll
        for (int k = 0; k < 8; ++k) a[k] = 0.f;
        for (int c = 0; c < 128; ++c) {
            float w = wq[c];
            const float* grow = Gb + c * 128 + c20;
#pragma unroll
            for (int k = 0; k < 8; ++k) a[k] = fmaf(w, grow[k], a[k]);
        }
#pragma unroll
        for (int k = 0; k < 8; ++k) t1[i * 132 + c20 + k] = a[k];
    }
    __syncthreads();
    {
        const int i = t >> 4, j = t & 15;
        const float* wk = qkv_w + (size_t)(128 + h * 16 + j) * 128;
        float s = 0.f;
        for (int c2 = 0; c2 < 128; ++c2) s = fmaf(t1[i * 132 + c2], wk[c2], s);
        sg[i * 16 + j] = s * 0.25f;
    }
    __syncthreads();
    if (t < 16) {
        float mx = -1e30f;
#pragma unroll
        for (int j = 0; j < 16; ++j) mx = fmaxf(mx, sg[t * 16 + j]);
        float e[16], sum = 0.f;
#pragma unroll
        for (int j = 0; j < 16; ++j) { e[j] = expf(sg[t * 16 + j] - mx); sum += e[j]; }
        float inv = 1.0f / sum;
#pragma unroll
        for (int j = 0; j < 16; ++j)
            attn[((size_t)bh * 16 + t) * 16 + j] = e[j] * inv;
    }
}

// ---------- fold: Mbb[b][o][c] = bf16( (P . blockdiag(attn) . Wv)[o][c] ) ----------
__global__ __launch_bounds__(256, 2) void k_mfold(const float* __restrict__ attn,
                                                  const float* __restrict__ qkv_w,
                                                  const float* __restrict__ PT,
                                                  ushort* __restrict__ Mbb) {
    __shared__ float t2[128 * 128];
    const int b = blockIdx.x, t = threadIdx.x;
    {
        const int hi = t >> 1, c0 = (t & 1) * 64;
        const int h = hi >> 4;
        const float* at = attn + ((size_t)b * 128 + hi) * 16;
        float a[16];
#pragma unroll
        for (int j = 0; j < 16; ++j) a[j] = at[j];
        float sc[64];
#pragma unroll
        for (int c = 0; c < 64; ++c) sc[c] = 0.f;
        for (int j = 0; j < 16; ++j) {
            const float* wv = qkv_w + (size_t)(256 + h * 16 + j) * 128 + c0;
            float aj = a[j];
#pragma unroll
            for (int c = 0; c < 64; ++c) sc[c] = fmaf(aj, wv[c], sc[c]);
        }
#pragma unroll
        for (int c = 0; c < 64; ++c) t2[hi * 128 + c0 + c] = sc[c];
    }
    __syncthreads();
    const int c = t & 127, half = t >> 7;
    float acc[128];
#pragma unroll
    for (int o = 0; o < 128; ++o) acc[o] = 0.f;
    for (int ci = half * 64; ci < half * 64 + 64; ++ci) {
        float s = t2[ci * 128 + c];
        const float* pt = PT + ci * 128;
#pragma unroll
        for (int o = 0; o < 128; ++o) acc[o] = fmaf(pt[o], s, acc[o]);
    }
    __syncthreads();
    if (half) {
#pragma unroll
        for (int o = 0; o < 128; ++o) t2[c * 128 + o] = acc[o];
    }
    __syncthreads();
    if (!half) {
        ushort* m = Mbb + (size_t)b * 16384;
#pragma unroll
        for (int o = 0; o < 128; ++o)
            m[(size_t)o * 128 + c] = f2b(acc[o] + t2[c * 128 + o]);
    }
}

// ---------- attnproj: x1pre = Mb x + proj_b + x -> x1Tb[b][n][c] bf16, LN1 stats ----------
// 128-n tile (R8 geometry); staging batched 16 loads in flight; bf16 output.
__global__ __launch_bounds__(256, 3) void k_attnproj(const float* __restrict__ x,
                                                     const ushort* __restrict__ Mbb,
                                                     const float* __restrict__ proj_b,
                                                     ushort* __restrict__ x1Tb,
                                                     float* __restrict__ st) {
    __shared__ ushort xT[128 * 136];   // [n][c] bf16, pad 136
    const int b = blockIdx.y;
    const int n0 = blockIdx.x * 128;
    const int t = threadIdx.x;
    const int wave = t >> 6, lane = t & 63, q = lane >> 4, r = lane & 15;
    {
        const int nn = t & 127, cg = t >> 7;
        const float* xp = x + (size_t)b * DS + n0 + nn;
        for (int gb = 0; gb < 4; ++gb) {
            float xv[16];
#pragma unroll
            for (int u = 0; u < 16; ++u)
                xv[u] = xp[(size_t)(cg * 64 + gb * 16 + u) * N_SP];
#pragma unroll
            for (int u4 = 0; u4 < 4; ++u4) {
                int c0 = cg * 64 + gb * 16 + u4 * 4;
                ushort4 pk;
                pk.x = f2b(xv[u4 * 4 + 0]); pk.y = f2b(xv[u4 * 4 + 1]);
                pk.z = f2b(xv[u4 * 4 + 2]); pk.w = f2b(xv[u4 * 4 + 3]);
                *(ushort4*)&xT[nn * 136 + c0] = pk;
            }
        }
    }
    const int orow = wave * 32 + r;
    // prefetch the wave's Mb slice: 8 independent loads (overlaps barrier)
    s8b a[8];
    {
        const ushort* mp = Mbb + (size_t)b * 16384 + (size_t)orow * 128 + q * 8;
#pragma unroll
        for (int m = 0; m < 2; ++m)
#pragma unroll
            for (int kk = 0; kk < 4; ++kk)
                a[m * 4 + kk] = *(const s8b*)(mp + m * 16 * 128 + kk * 32);
    }
    __syncthreads();
    f4 acc[2][8];
#pragma unroll
    for (int m = 0; m < 2; ++m)
#pragma unroll
        for (int j = 0; j < 8; ++j) acc[m][j] = (f4){0,0,0,0};
#pragma unroll
    for (int kk = 0; kk < 4; ++kk) {
        const int c0 = kk * 32 + q * 8;
#pragma unroll
        for (int j = 0; j < 8; ++j) {
            s8b bx = *(const s8b*)&xT[(j * 16 + r) * 136 + c0];
            acc[0][j] = __builtin_amdgcn_mfma_f32_16x16x32_bf16(a[kk],     bx, acc[0][j], 0, 0, 0);
            acc[1][j] = __builtin_amdgcn_mfma_f32_16x16x32_bf16(a[4 + kk], bx, acc[1][j], 0, 0, 0);
        }
    }
    float s = 0.f, sq = 0.f;
    float4 pbq0 = *(const float4*)&proj_b[wave * 32 + q * 4];
    float4 pbq1 = *(const float4*)&proj_b[wave * 32 + 16 + q * 4];
#pragma unroll
    for (int m = 0; m < 2; ++m) {
        const int o0 = wave * 32 + m * 16 + q * 4;
        const float4 pb = m ? pbq1 : pbq0;
#pragma unroll
        for (int j = 0; j < 8; ++j) {
            const int nn = j * 16 + r;
            ushort4 xr = *(const ushort4*)&xT[nn * 136 + o0];
            float v0 = acc[m][j][0] + pb.x + b2f(xr.x);
            float v1 = acc[m][j][1] + pb.y + b2f(xr.y);
            float v2 = acc[m][j][2] + pb.z + b2f(xr.z);
            float v3 = acc[m][j][3] + pb.w + b2f(xr.w);
            ushort4 ov;
            ov.x = f2b(v0); ov.y = f2b(v1); ov.z = f2b(v2); ov.w = f2b(v3);
            *(ushort4*)(x1Tb + (size_t)b * DS + (size_t)(n0 + nn) * 128 + o0) = ov;
            s += (v0 + v1) + (v2 + v3);
            sq = fmaf(v0, v0, sq); sq = fmaf(v1, v1, sq);
            sq = fmaf(v2, v2, sq); sq = fmaf(v3, v3, sq);
        }
    }
#pragma unroll
    for (int off = 32; off > 0; off >>= 1) {
        s += __shfl_down(s, off, 64);
        sq += __shfl_down(sq, off, 64);
    }
    if (lane == 0) {
        atomicAdd(&st[0 + b], s);
        atomicAdd(&st[8 + b], sq);
    }
}

__global__ void k_finalize(float* st, int off) {
    int b = threadIdx.x;
    if (b < 8) {
        const float invn = 1.0f / 4194304.0f;
        float mu = st[off + b] * invn;
        float var = st[off + 8 + b] * invn - mu * mu;
        st[off + 16 + b] = mu;
        st[off + 24 + b] = rsqrtf(var + 1e-5f);
    }
}

// ---------- LN2 apply with packed bf16 params ----------
__global__ __launch_bounds__(256) void k_lnapply(const float* __restrict__ in,
                                                 const uint* __restrict__ lnwb,
                                                 const float* __restrict__ st, int off,
                                                 float* __restrict__ out) {
    size_t i4 = (size_t)blockIdx.x * 256 + threadIdx.x;
    int b = (int)(i4 >> 20);
    size_t cn = i4 * 4 - (size_t)b * 4194304;
    float mu = st[off + 16 + b], rs = st[off + 24 + b];
    const float4 xv = *(const float4*)(in + (size_t)b * DS + cn);
    const uint4 wv = *(const uint4*)(lnwb + cn);
    float4 o;
    o.x = fmaf((xv.x - mu) * rs, b2f((ushort)(wv.x & 0xffffu)), b2f((ushort)(wv.x >> 16)));
    o.y = fmaf((xv.y - mu) * rs, b2f((ushort)(wv.y & 0xffffu)), b2f((ushort)(wv.y >> 16)));
    o.z = fmaf((xv.z - mu) * rs, b2f((ushort)(wv.z & 0xffffu)), b2f((ushort)(wv.z >> 16)));
    o.w = fmaf((xv.w - mu) * rs, b2f((ushort)(wv.w & 0xffffu)), b2f((ushort)(wv.w >> 16)));
    *(float4*)(out + (size_t)b * DS + cn) = o;
}

// ---------- fused LN1-apply + MLP + residual + LN2 stats, 128-n tile ----------
// R8 geometry. Staging from bf16 x1Tb, batched 12 loads in flight per group.
__global__ __launch_bounds__(256, 2) void k_mlp(const ushort* __restrict__ x1Tb,
                                                float* __restrict__ xout,
                                                const ushort* __restrict__ w1b,
                                                const float* __restrict__ b1v,
                                                const ushort* __restrict__ w2b,
                                                const float* __restrict__ b2v,
                                                const uint* __restrict__ lnwbT,
                                                float* __restrict__ st) {
    __shared__ ushort xT[128 * 128];   // swizzled, x1 = LN1(x1pre) bf16
    __shared__ ushort hT[128 * 128];   // swizzled, gelu os-slice [n][hr] bf16
    const int b = blockIdx.y;
    const int n0 = blockIdx.x * 128;
    const int t = threadIdx.x;
    const int wave = t >> 6, lane = t & 63, q = lane >> 4, r = lane & 15;
    const float mu = st[16 + b], rs = st[24 + b];
    {
        // 16 col-groups of 8 c x 16 rows/pass; 2 batches of 4 rows, 12 loads in flight
        const int c8 = (t & 15) * 8, rb = t >> 4;
        const ushort* xb = x1Tb + (size_t)b * DS + (size_t)n0 * 128;
        const uint*  wb = lnwbT + (size_t)n0 * 128;
#pragma unroll
        for (int gb = 0; gb < 2; ++gb) {
            s8b xv[4]; uint4 wv0[4], wv1[4];
#pragma unroll
            for (int u = 0; u < 4; ++u) {
                int nn = (gb * 4 + u) * 16 + rb;
                xv[u]  = *(const s8b*)(xb + (size_t)nn * 128 + c8);
                wv0[u] = *(const uint4*)(wb + (size_t)nn * 128 + c8);
                wv1[u] = *(const uint4*)(wb + (size_t)nn * 128 + c8 + 4);
            }
#pragma unroll
            for (int u = 0; u < 4; ++u) {
                int nn = (gb * 4 + u) * 16 + rb;
                ushort4 p0, p1;
                float xe;
                xe = b2f((ushort)xv[u][0]);
                p0.x = f2b(fmaf((xe - mu) * rs, b2f((ushort)(wv0[u].x & 0xffffu)), b2f((ushort)(wv0[u].x >> 16))));
                xe = b2f((ushort)xv[u][1]);
                p0.y = f2b(fmaf((xe - mu) * rs, b2f((ushort)(wv0[u].y & 0xffffu)), b2f((ushort)(wv0[u].y >> 16))));
                xe = b2f((ushort)xv[u][2]);
                p0.z = f2b(fmaf((xe - mu) * rs, b2f((ushort)(wv0[u].z & 0xffffu)), b2f((ushort)(wv0[u].z >> 16))));
                xe = b2f((ushort)xv[u][3]);
                p0.w = f2b(fmaf((xe - mu) * rs, b2f((ushort)(wv0[u].w & 0xffffu)), b2f((ushort)(wv0[u].w >> 16))));
                xe = b2f((ushort)xv[u][4]);
                p1.x = f2b(fmaf((xe - mu) * rs, b2f((ushort)(wv1[u].x & 0xffffu)), b2f((ushort)(wv1[u].x >> 16))));
                xe = b2f((ushort)xv[u][5]);
                p1.y = f2b(fmaf((xe - mu) * rs, b2f((ushort)(wv1[u].y & 0xffffu)), b2f((ushort)(wv1[u].y >> 16))));
                xe = b2f((ushort)xv[u][6]);
                p1.z = f2b(fmaf((xe - mu) * rs, b2f((ushort)(wv1[u].z & 0xffffu)), b2f((ushort)(wv1[u].z >> 16))));
                xe = b2f((ushort)xv[u][7]);
                p1.w = f2b(fmaf((xe - mu) * rs, b2f((ushort)(wv1[u].w & 0xffffu)), b2f((ushort)(wv1[u].w >> 16))));
                *(ushort4*)&xT[swz4(nn, c8)] = p0;
                *(ushort4*)&xT[swz4(nn, c8 + 4)] = p1;
            }
        }
    }
    const int orow = wave * 32 + r;
    // prefetch GEMM1 A-slice for os=0 (8 independent loads), overlaps barrier
    s8b a1[8];
    {
        const ushort* w1p = w1b + (size_t)orow * 128 + q * 8;
#pragma unroll
        for (int m = 0; m < 2; ++m)
#pragma unroll
            for (int kk = 0; kk < 4; ++kk)
                a1[m * 4 + kk] = *(const s8b*)(w1p + m * 16 * 128 + kk * 32);
    }
    __syncthreads();
    f4 acc2[2][8];
#pragma unroll
    for (int m = 0; m < 2; ++m)
#pragma unroll
        for (int j = 0; j < 8; ++j) acc2[m][j] = (f4){0,0,0,0};

    for (int os = 0; os < 4; ++os) {
        // ---- GEMM1: h[os-slice rows owned by wave] = W1 x1 ----
        f4 acc1[2][8];
#pragma unroll
        for (int m = 0; m < 2; ++m)
#pragma unroll
            for (int j = 0; j < 8; ++j) acc1[m][j] = (f4){0,0,0,0};
#pragma unroll
        for (int kk = 0; kk < 4; ++kk) {
            const int c0 = kk * 32 + q * 8;
#pragma unroll
            for (int j = 0; j < 8; ++j) {
                s8b bx = *(const s8b*)&xT[swz8(j * 16 + r, c0)];
                acc1[0][j] = __builtin_amdgcn_mfma_f32_16x16x32_bf16(a1[kk],     bx, acc1[0][j], 0, 0, 0);
                acc1[1][j] = __builtin_amdgcn_mfma_f32_16x16x32_bf16(a1[4 + kk], bx, acc1[1][j], 0, 0, 0);
            }
        }
        // prefetch GEMM2 A-slice for this os (independent of hT)
        s8b a2[8];
        {
            const ushort* w2p = w2b + (size_t)orow * 512 + os * 128 + q * 8;
#pragma unroll
            for (int m = 0; m < 2; ++m)
#pragma unroll
                for (int kk = 0; kk < 4; ++kk)
                    a2[m * 4 + kk] = *(const s8b*)(w2p + m * 16 * 512 + kk * 32);
        }
        float4 b1q0 = *(const float4*)&b1v[os * 128 + wave * 32 + q * 4];
        float4 b1q1 = *(const float4*)&b1v[os * 128 + wave * 32 + 16 + q * 4];
        // ---- gelu -> hT (cross-wave) ----
#pragma unroll
        for (int m = 0; m < 2; ++m) {
            const int hr0 = wave * 32 + m * 16 + q * 4;
            const float4 bq = m ? b1q1 : b1q0;
#pragma unroll
            for (int j = 0; j < 8; ++j) {
                ushort4 pk;
                pk.x = f2b(gelu_f(acc1[m][j][0] + bq.x));
                pk.y = f2b(gelu_f(acc1[m][j][1] + bq.y));
                pk.z = f2b(gelu_f(acc1[m][j][2] + bq.z));
                pk.w = f2b(gelu_f(acc1[m][j][3] + bq.w));
                *(ushort4*)&hT[swz4(j * 16 + r, hr0)] = pk;
            }
        }
        __syncthreads();   // hT complete across waves
        // ---- GEMM2: acc2 += W2[:, os-slice] h ----
#pragma unroll
        for (int kk = 0; kk < 4; ++kk) {
            const int c0 = kk * 32 + q * 8;
#pragma unroll
            for (int j = 0; j < 8; ++j) {
                s8b hx = *(const s8b*)&hT[swz8(j * 16 + r, c0)];
                acc2[0][j] = __builtin_amdgcn_mfma_f32_16x16x32_bf16(a2[kk],     hx, acc2[0][j], 0, 0, 0);
                acc2[1][j] = __builtin_amdgcn_mfma_f32_16x16x32_bf16(a2[4 + kk], hx, acc2[1][j], 0, 0, 0);
            }
        }
        // prefetch next os's GEMM1 A-slice (overlaps barrier drain)
        if (os < 3) {
            const ushort* w1p = w1b + (size_t)((os + 1) * 128 + orow) * 128 + q * 8;
#pragma unroll
            for (int m = 0; m < 2; ++m)
#pragma unroll
                for (int kk = 0; kk < 4; ++kk)
                    a1[m * 4 + kk] = *(const s8b*)(w1p + m * 16 * 128 + kk * 32);
        }
        __syncthreads();   // hT consumed; safe to overwrite next os
    }
    // ---- epilogue: residual + b2, strided store to out[c][n], LN2 stats ----
    float s = 0.f, sq = 0.f;
    float4 b2q0 = *(const float4*)&b2v[wave * 32 + q * 4];
    float4 b2q1 = *(const float4*)&b2v[wave * 32 + 16 + q * 4];
#pragma unroll
    for (int m = 0; m < 2; ++m) {
        const int o0 = wave * 32 + m * 16 + q * 4;
        const float4 bq = m ? b2q1 : b2q0;
#pragma unroll
        for (int j = 0; j < 8; ++j) {
            const int nn = j * 16 + r;
            ushort4 xr = *(const ushort4*)&xT[swz4(nn, o0)];
            float v0 = acc2[m][j][0] + bq.x + b2f(xr.x);
            float v1 = acc2[m][j][1] + bq.y + b2f(xr.y);
            float v2 = acc2[m][j][2] + bq.z + b2f(xr.z);
            float v3 = acc2[m][j][3] + bq.w + b2f(xr.w);
            float* op = xout + (size_t)b * DS + n0 + nn;
            op[(size_t)(o0 + 0) * N_SP] = v0;
            op[(size_t)(o0 + 1) * N_SP] = v1;
            op[(size_t)(o0 + 2) * N_SP] = v2;
            op[(size_t)(o0 + 3) * N_SP] = v3;
            s += (v0 + v1) + (v2 + v3);
            sq = fmaf(v0, v0, sq); sq = fmaf(v1, v1, sq);
            sq = fmaf(v2, v2, sq); sq = fmaf(v3, v3, sq);
        }
    }
#pragma unroll
    for (int off = 32; off > 0; off >>= 1) {
        s += __shfl_down(s, off, 64);
        sq += __shfl_down(sq, off, 64);
    }
    if (lane == 0) {
        atomicAdd(&st[32 + b], s);
        atomicAdd(&st[40 + b], sq);
    }
}

extern "C" void kernel_launch(void* const* d_in, const int* in_sizes, int n_in,
                              void* d_out, int out_size, void* d_ws, size_t ws_size,
                              hipStream_t stream) {
    const float* x      = (const float*)d_in[0];
    const float* qkv_w  = (const float*)d_in[1];
    const float* proj_w = (const float*)d_in[2];
    const float* proj_b = (const float*)d_in[3];
    const float* ln1_w  = (const float*)d_in[4];
    const float* ln1_b  = (const float*)d_in[5];
    const float* ln2_w  = (const float*)d_in[6];
    const float* ln2_b  = (const float*)d_in[7];
    const float* mlp_w1 = (const float*)d_in[8];
    const float* mlp_b1 = (const float*)d_in[9];
    const float* mlp_w2 = (const float*)d_in[10];
    const float* mlp_b2 = (const float*)d_in[11];
    float* out = (float*)d_out;

    char* wsb = (char*)d_ws;
    // small persistent region
    float*  st    = (float*)wsb;                      // 256 B
    float*  attn  = (float*)(wsb + 256);              // 65,536
    float*  PT    = (float*)(wsb + 65792);            // 65,536
    ushort* Mbb   = (ushort*)(wsb + 131328);          // 262,144
    ushort* w1b   = (ushort*)(wsb + 393472);          // 131,072
    ushort* w2b   = (ushort*)(wsb + 524544);          // 131,072
    float*  G     = (float*)(wsb + 655616);           // 524,288
    uint*   lnwbT = (uint*)(wsb + 1179904);           // 16,777,216
    // big dual-use region (stream-ordered lifetimes):
    //   Gpart (67MB, dead after k_greduce) -> x1Tb bf16 (67MB, dead after k_mlp)
    //   -> lnwb2 (16MB, for k_lnapply)
    float*  Gpart = (float*)(wsb + 18874368);         // 67,108,864
    ushort* x1Tb  = (ushort*)(wsb + 18874368);        // 67,108,864
    uint*   lnwb2 = (uint*)(wsb + 18874368);          // 16,777,216

    hipMemsetAsync(st, 0, 64 * sizeof(float), stream);

    k_transpose<<<64, 256, 0, stream>>>(proj_w, PT, 128, 128);
    k_cvt<<<256, 256, 0, stream>>>(mlp_w1, w1b, 65536);
    k_cvt<<<256, 256, 0, stream>>>(mlp_w2, w2b, 65536);
    k_packln<<<16384, 256, 0, stream>>>(ln1_w, ln1_b, lnwbT);

    k_cov<<<dim3(128, 8), 256, 0, stream>>>(x, Gpart);
    k_greduce<<<512, 256, 0, stream>>>(Gpart, G);
    k_gram_small<<<64, 256, 0, stream>>>(G, qkv_w, attn);
    k_mfold<<<8, 256, 0, stream>>>(attn, qkv_w, PT, Mbb);

    k_attnproj<<<dim3(256, 8), 256, 0, stream>>>(x, Mbb, proj_b, x1Tb, st);
    k_finalize<<<1, 64, 0, stream>>>(st, 0);
    k_mlp<<<dim3(256, 8), 256, 0, stream>>>(x1Tb, out, w1b, mlp_b1, w2b, mlp_b2,
                                            lnwbT, st);
    // x1Tb dead; pack LN2 params into the same region for the final apply
    k_packflat<<<16384, 256, 0, stream>>>(ln2_w, ln2_b, lnwb2);
    k_finalize<<<1, 64, 0, stream>>>(st, 32);
    k_lnapply<<<32768, 256, 0, stream>>>(out, lnwb2, st, 32, out);
}

// Round 7
// 953.314 us; speedup vs baseline: 1.4562x; 1.0182x over previous
//
#include <hip/hip_runtime.h>
#include <hip/hip_bf16.h>
#include <math.h>

// TransformerBlock3D: B=8, C=128, S=32 (N=32768), HEADS=8 (dim_head=16), MLP=512
// Round 11: L2 working-set protection + partial-sum traffic cut.
//  Evidence (R10): k_mlp FETCH = 67MB x1Tb + ~20MB weight REFETCH (256KB set
//  re-fetched ~78x: streams evict weights from 4MB/XCD L2); fetch-volume cut
//  alone gave ~0 -> the lever is miss LATENCY on the per-os weight loads.
//  - nontemporal loads/stores on all streaming traffic (x, x1Tb, out, Gpart)
//    so weights/Mbb stay L2-resident.
//  - k_cov: 512-n blocks (grid 512, 4 ch iters) -> Gpart 33.5MB (-67MB rtrip).
//  - k_attnproj: 16 nt float4 loads + 4x4 reg transpose staging (was 64 loads).
//  - k_mlp: b1/b2 folded into MFMA acc init (saves ~128 VALU adds/wave).
// Math: G=XX^T, attn=softmax(0.25*WqGWk^T), Mb=P.blockdiag(attn).Wv (bf16),
//       x1pre = Mb x + proj_b + x; x1 = LN1(x1pre); x2pre = x1 + b2 + W2 gelu(W1 x1 + b1).

#define N_SP 32768
typedef __hip_bfloat16 bf16;
static const size_t DS = (size_t)128 * N_SP;

typedef __attribute__((ext_vector_type(8))) short s8b;
typedef __attribute__((ext_vector_type(4))) float f4;
typedef __attribute__((ext_vector_type(4))) uint u4v;
typedef __attribute__((ext_vector_type(4))) ushort us4v;

__device__ __forceinline__ ushort f2b(float f) {
    __hip_bfloat16 h = __float2bfloat16(f);
    return *reinterpret_cast<ushort*>(&h);
}
__device__ __forceinline__ float b2f(ushort u) {
    unsigned v = ((unsigned)u) << 16;
    float f;
    __builtin_memcpy(&f, &v, 4);
    return f;
}
__device__ __forceinline__ float gelu_f(float h) {
    float u = 1.5957691216057308f * h * fmaf(0.044715f, h * h, 1.0f);
    float e = __expf(u);
    return h * (1.0f - __builtin_amdgcn_rcpf(e + 1.0f));
}
// swizzled index for 128-col bf16 LDS tiles (c0 multiple of 8)
__device__ __forceinline__ int swz8(int n, int c0) {
    return n * 128 + (c0 ^ ((n & 15) << 3));
}
// swizzled index, c0 multiple of 4
__device__ __forceinline__ int swz4(int n, int c0) {
    return n * 128 + (((c0 & 0x78) ^ ((n & 15) << 3)) | (c0 & 4));
}

// ---------- tiny transpose ----------
__global__ __launch_bounds__(256) void k_transpose(const float* __restrict__ in,
                                                   float* __restrict__ out,
                                                   int R, int Ccols) {
    int idx = blockIdx.x * 256 + threadIdx.x;
    if (idx >= R * Ccols) return;
    int r = idx / Ccols, c = idx % Ccols;
    out[c * R + r] = in[idx];
}

// ---------- fp32 -> bf16 ----------
__global__ __launch_bounds__(256) void k_cvt(const float* __restrict__ in,
                                             ushort* __restrict__ out, int n) {
    int i = blockIdx.x * 256 + threadIdx.x;
    if (i < n) out[i] = f2b(in[i]);
}

// ---------- pack LN1 w/b (f32 [c][n]) -> bf16 pair (uint, [n][c]) ----------
__global__ __launch_bounds__(256) void k_packln(const float* __restrict__ w,
                                                const float* __restrict__ b,
                                                uint* __restrict__ out) {
    int tid = blockIdx.x * 256 + threadIdx.x;        // 4,194,304 elements
    int c = tid >> 15, n = tid & 32767;
    uint lo = f2b(w[tid]);
    uint hi = f2b(b[tid]);
    out[(size_t)n * 128 + c] = lo | (hi << 16);
}

// ---------- pack LN2 w/b (f32) -> bf16 pair (uint), same layout ----------
__global__ __launch_bounds__(256) void k_packflat(const float* __restrict__ w,
                                                  const float* __restrict__ b,
                                                  uint* __restrict__ out) {
    int tid = blockIdx.x * 256 + threadIdx.x;        // 4,194,304 elements
    uint lo = f2b(w[tid]);
    uint hi = f2b(b[tid]);
    out[tid] = lo | (hi << 16);
}

// ---------- covariance partials via MFMA: Gpart[b*64+kb] = X Xs^T over 512 n ----------
__global__ __launch_bounds__(256, 4) void k_cov(const float* __restrict__ x,
                                                float* __restrict__ Gpart) {
    __shared__ ushort xs[128 * 136];   // [c][n_local], pad 136 (16B-aligned rows)
    const int kb = blockIdx.x, b = blockIdx.y;
    const int t = threadIdx.x;
    const int wave = t >> 6, lane = t & 63, q = lane >> 4, r = lane & 15;
    f4 acc[8][2];
#pragma unroll
    for (int m = 0; m < 8; ++m) { acc[m][0] = (f4){0,0,0,0}; acc[m][1] = (f4){0,0,0,0}; }
    for (int ch = 0; ch < 4; ++ch) {
        const int nbase = kb * 512 + ch * 128;
        __syncthreads();
        {
            // nt float4-over-n staging, batched 8 loads in flight
            const int nq = t & 31, cr = t >> 5;      // 32 n-quads, 8 c-rows
            const float* xp = x + (size_t)b * DS + nbase + nq * 4;
#pragma unroll
            for (int half = 0; half < 2; ++half) {
                f4 xv[8];
#pragma unroll
                for (int cc = 0; cc < 8; ++cc)
                    xv[cc] = __builtin_nontemporal_load(
                        (const f4*)(xp + (size_t)(cr * 16 + half * 8 + cc) * N_SP));
#pragma unroll
                for (int cc = 0; cc < 8; ++cc) {
                    int c = cr * 16 + half * 8 + cc;
                    ushort4 pk;
                    pk.x = f2b(xv[cc].x); pk.y = f2b(xv[cc].y);
                    pk.z = f2b(xv[cc].z); pk.w = f2b(xv[cc].w);
                    *(ushort4*)&xs[c * 136 + nq * 4] = pk;
                }
            }
        }
        __syncthreads();
        for (int kk = 0; kk < 4; ++kk) {
            const int c0 = kk * 32 + q * 8;
            s8b bj0 = *(const s8b*)&xs[(wave * 32 + r) * 136 + c0];
            s8b bj1 = *(const s8b*)&xs[(wave * 32 + 16 + r) * 136 + c0];
#pragma unroll
            for (int m = 0; m < 8; ++m) {
                s8b a = *(const s8b*)&xs[(m * 16 + r) * 136 + c0];
                acc[m][0] = __builtin_amdgcn_mfma_f32_16x16x32_bf16(a, bj0, acc[m][0], 0, 0, 0);
                acc[m][1] = __builtin_amdgcn_mfma_f32_16x16x32_bf16(a, bj1, acc[m][1], 0, 0, 0);
            }
        }
    }
    float* gp = Gpart + ((size_t)b * 64 + kb) * 16384;
#pragma unroll
    for (int n2 = 0; n2 < 2; ++n2)
#pragma unroll
        for (int m = 0; m < 8; ++m)
#pragma unroll
            for (int rg = 0; rg < 4; ++rg) {
                int i = m * 16 + q * 4 + rg;
                int j = wave * 32 + n2 * 16 + r;
                gp[i * 128 + j] = acc[m][n2][rg];
            }
}

__global__ __launch_bounds__(256) void k_greduce(const float* __restrict__ Gpart,
                                                 float* __restrict__ G) {
    int tid = blockIdx.x * 256 + threadIdx.x;
    int b = tid >> 14, ij = tid & 16383;
    float s = 0.f;
#pragma unroll 8
    for (int kb = 0; kb < 64; ++kb)
        s += __builtin_nontemporal_load(&Gpart[((size_t)b * 64 + kb) * 16384 + ij]);
    G[tid] = s;
}

// ---------- gram + softmax ----------
__global__ __launch_bounds__(256) void k_gram_small(const float* __restrict__ G,
                                                    const float* __restrict__ qkv_w,
                                                    float* __restrict__ attn) {
    __shared__ float t1[16 * 132];
    __shared__ float sg[16 * 16];
    const int bh = blockIdx.x;
    const int b = bh >> 3, h = bh & 7;
    const int t = threadIdx.x;
    {
        const int i = t >> 4, c20 = (t & 15) * 8;
        const float* wq = qkv_w + (size_t)(h * 16 + i) * 128;
        const float* Gb = G + (size_t)b * 16384;
        float a[8];
#pragma unroll
        for (int k = 0; k < 8; ++k) a[k] = 0.f;
        for (int c = 0; c < 128; ++c) {
            float w = wq[c];
            const float* grow = Gb + c * 128 + c20;
#pragma unroll
            for (int k = 0; k < 8; ++k) a[k] = fmaf(w, grow[k], a[k]);
        }
#pragma unroll
        for (int k = 0; k < 8; ++k) t1[i * 132 + c20 + k] = a[k];
    }
    __syncthreads();
    {
        const int i = t >> 4, j = t & 15;
        const float* wk = qkv_w + (size_t)(128 + h * 16 + j) * 128;
        float s = 0.f;
        for (int c2 = 0; c2 < 128; ++c2) s = fmaf(t1[i * 132 + c2], wk[c2], s);
        sg[i * 16 + j] = s * 0.25f;
    }
    __syncthreads();
    if (t < 16) {
        float mx = -1e30f;
#pragma unroll
        for (int j = 0; j < 16; ++j) mx = fmaxf(mx, sg[t * 16 + j]);
        float e[16], sum = 0.f;
#pragma unroll
        for (int j = 0; j < 16; ++j) { e[j] = expf(sg[t * 16 + j] - mx); sum += e[j]; }
        float inv = 1.0f / sum;
#pragma unroll
        for (int j = 0; j < 16; ++j)
            attn[((size_t)bh * 16 + t) * 16 + j] = e[j] * inv;
    }
}

// ---------- fold: Mbb[b][o][c] = bf16( (P . blockdiag(attn) . Wv)[o][c] ) ----------
__global__ __launch_bounds__(256, 2) void k_mfold(const float* __restrict__ attn,
                                                  const float* __restrict__ qkv_w,
                                                  const float* __restrict__ PT,
                                                  ushort* __restrict__ Mbb) {
    __shared__ float t2[128 * 128];
    const int b = blockIdx.x, t = threadIdx.x;
    {
        const int hi = t >> 1, c0 = (t & 1) * 64;
        const int h = hi >> 4;
        const float* at = attn + ((size_t)b * 128 + hi) * 16;
        float a[16];
#pragma unroll
        for (int j = 0; j < 16; ++j) a[j] = at[j];
        float sc[64];
#pragma unroll
        for (int c = 0; c < 64; ++c) sc[c] = 0.f;
        for (int j = 0; j < 16; ++j) {
            const float* wv = qkv_w + (size_t)(256 + h * 16 + j) * 128 + c0;
            float aj = a[j];
#pragma unroll
            for (int c = 0; c < 64; ++c) sc[c] = fmaf(aj, wv[c], sc[c]);
        }
#pragma unroll
        for (int c = 0; c < 64; ++c) t2[hi * 128 + c0 + c] = sc[c];
    }
    __syncthreads();
    const int c = t & 127, half = t >> 7;
    float acc[128];
#pragma unroll
    for (int o = 0; o < 128; ++o) acc[o] = 0.f;
    for (int ci = half * 64; ci < half * 64 + 64; ++ci) {
        float s = t2[ci * 128 + c];
        const float* pt = PT + ci * 128;
#pragma unroll
        for (int o = 0; o < 128; ++o) acc[o] = fmaf(pt[o], s, acc[o]);
    }
    __syncthreads();
    if (half) {
#pragma unroll
        for (int o = 0; o < 128; ++o) t2[c * 128 + o] = acc[o];
    }
    __syncthreads();
    if (!half) {
        ushort* m = Mbb + (size_t)b * 16384;
#pragma unroll
        for (int o = 0; o < 128; ++o)
            m[(size_t)o * 128 + c] = f2b(acc[o] + t2[c * 128 + o]);
    }
}

// ---------- attnproj: x1pre = Mb x + proj_b + x -> x1Tb[b][n][c] bf16, LN1 stats ----------
// 128-n tile; staging = 16 nt float4 loads + 4x4 register transpose.
__global__ __launch_bounds__(256, 3) void k_attnproj(const float* __restrict__ x,
                                                     const ushort* __restrict__ Mbb,
                                                     const float* __restrict__ proj_b,
                                                     ushort* __restrict__ x1Tb,
                                                     float* __restrict__ st) {
    __shared__ ushort xT[128 * 136];   // [n][c] bf16, pad 136
    const int b = blockIdx.y;
    const int n0 = blockIdx.x * 128;
    const int t = threadIdx.x;
    const int wave = t >> 6, lane = t & 63, q = lane >> 4, r = lane & 15;
    {
        const int nq = (t & 31) * 4;                 // 32 n-quads cover 128 n
        const int cg = (t >> 5) * 4;                 // 8 c-quads base
        const float* xb = x + (size_t)b * DS + n0 + nq;
#pragma unroll
        for (int ph = 0; ph < 2; ++ph) {
            f4 xv[8];
#pragma unroll
            for (int u = 0; u < 8; ++u) {
                int c = ph * 64 + cg + (u >> 2) * 32 + (u & 3);
                xv[u] = __builtin_nontemporal_load((const f4*)(xb + (size_t)c * N_SP));
            }
#pragma unroll
            for (int u2 = 0; u2 < 2; ++u2) {
                int c0 = ph * 64 + cg + u2 * 32;
#pragma unroll
                for (int i = 0; i < 4; ++i) {
                    us4v pk = { f2b(xv[u2 * 4 + 0][i]), f2b(xv[u2 * 4 + 1][i]),
                                f2b(xv[u2 * 4 + 2][i]), f2b(xv[u2 * 4 + 3][i]) };
                    *(us4v*)&xT[(nq + i) * 136 + c0] = pk;
                }
            }
        }
    }
    const int orow = wave * 32 + r;
    // prefetch the wave's Mb slice: 8 independent loads (overlaps barrier)
    s8b a[8];
    {
        const ushort* mp = Mbb + (size_t)b * 16384 + (size_t)orow * 128 + q * 8;
#pragma unroll
        for (int m = 0; m < 2; ++m)
#pragma unroll
            for (int kk = 0; kk < 4; ++kk)
                a[m * 4 + kk] = *(const s8b*)(mp + m * 16 * 128 + kk * 32);
    }
    __syncthreads();
    f4 acc[2][8];
#pragma unroll
    for (int m = 0; m < 2; ++m)
#pragma unroll
        for (int j = 0; j < 8; ++j) acc[m][j] = (f4){0,0,0,0};
#pragma unroll
    for (int kk = 0; kk < 4; ++kk) {
        const int c0 = kk * 32 + q * 8;
#pragma unroll
        for (int j = 0; j < 8; ++j) {
            s8b bx = *(const s8b*)&xT[(j * 16 + r) * 136 + c0];
            acc[0][j] = __builtin_amdgcn_mfma_f32_16x16x32_bf16(a[kk],     bx, acc[0][j], 0, 0, 0);
            acc[1][j] = __builtin_amdgcn_mfma_f32_16x16x32_bf16(a[4 + kk], bx, acc[1][j], 0, 0, 0);
        }
    }
    float s = 0.f, sq = 0.f;
    float4 pbq0 = *(const float4*)&proj_b[wave * 32 + q * 4];
    float4 pbq1 = *(const float4*)&proj_b[wave * 32 + 16 + q * 4];
#pragma unroll
    for (int m = 0; m < 2; ++m) {
        const int o0 = wave * 32 + m * 16 + q * 4;
        const float4 pb = m ? pbq1 : pbq0;
#pragma unroll
        for (int j = 0; j < 8; ++j) {
            const int nn = j * 16 + r;
            ushort4 xr = *(const ushort4*)&xT[nn * 136 + o0];
            float v0 = acc[m][j][0] + pb.x + b2f(xr.x);
            float v1 = acc[m][j][1] + pb.y + b2f(xr.y);
            float v2 = acc[m][j][2] + pb.z + b2f(xr.z);
            float v3 = acc[m][j][3] + pb.w + b2f(xr.w);
            us4v ov = { f2b(v0), f2b(v1), f2b(v2), f2b(v3) };
            __builtin_nontemporal_store(ov,
                (us4v*)(x1Tb + (size_t)b * DS + (size_t)(n0 + nn) * 128 + o0));
            s += (v0 + v1) + (v2 + v3);
            sq = fmaf(v0, v0, sq); sq = fmaf(v1, v1, sq);
            sq = fmaf(v2, v2, sq); sq = fmaf(v3, v3, sq);
        }
    }
#pragma unroll
    for (int off = 32; off > 0; off >>= 1) {
        s += __shfl_down(s, off, 64);
        sq += __shfl_down(sq, off, 64);
    }
    if (lane == 0) {
        atomicAdd(&st[0 + b], s);
        atomicAdd(&st[8 + b], sq);
    }
}

__global__ void k_finalize(float* st, int off) {
    int b = threadIdx.x;
    if (b < 8) {
        const float invn = 1.0f / 4194304.0f;
        float mu = st[off + b] * invn;
        float var = st[off + 8 + b] * invn - mu * mu;
        st[off + 16 + b] = mu;
        st[off + 24 + b] = rsqrtf(var + 1e-5f);
    }
}

// ---------- LN2 apply with packed bf16 params ----------
__global__ __launch_bounds__(256) void k_lnapply(const float* __restrict__ in,
                                                 const uint* __restrict__ lnwb,
                                                 const float* __restrict__ st, int off,
                                                 float* __restrict__ out) {
    size_t i4 = (size_t)blockIdx.x * 256 + threadIdx.x;
    int b = (int)(i4 >> 20);
    size_t cn = i4 * 4 - (size_t)b * 4194304;
    float mu = st[off + 16 + b], rs = st[off + 24 + b];
    const float4 xv = *(const float4*)(in + (size_t)b * DS + cn);
    const uint4 wv = *(const uint4*)(lnwb + cn);
    float4 o;
    o.x = fmaf((xv.x - mu) * rs, b2f((ushort)(wv.x & 0xffffu)), b2f((ushort)(wv.x >> 16)));
    o.y = fmaf((xv.y - mu) * rs, b2f((ushort)(wv.y & 0xffffu)), b2f((ushort)(wv.y >> 16)));
    o.z = fmaf((xv.z - mu) * rs, b2f((ushort)(wv.z & 0xffffu)), b2f((ushort)(wv.z >> 16)));
    o.w = fmaf((xv.w - mu) * rs, b2f((ushort)(wv.w & 0xffffu)), b2f((ushort)(wv.w >> 16)));
    *(float4*)(out + (size_t)b * DS + cn) = o;
}

// ---------- fused LN1-apply + MLP + residual + LN2 stats, 128-n tile ----------
// R8 geometry; nt staging loads; nt epilogue stores; biases in acc init.
__global__ __launch_bounds__(256, 2) void k_mlp(const ushort* __restrict__ x1Tb,
                                                float* __restrict__ xout,
                                                const ushort* __restrict__ w1b,
                                                const float* __restrict__ b1v,
                                                const ushort* __restrict__ w2b,
                                                const float* __restrict__ b2v,
                                                const uint* __restrict__ lnwbT,
                                                float* __restrict__ st) {
    __shared__ ushort xT[128 * 128];   // swizzled, x1 = LN1(x1pre) bf16
    __shared__ ushort hT[128 * 128];   // swizzled, gelu os-slice [n][hr] bf16
    const int b = blockIdx.y;
    const int n0 = blockIdx.x * 128;
    const int t = threadIdx.x;
    const int wave = t >> 6, lane = t & 63, q = lane >> 4, r = lane & 15;
    const float mu = st[16 + b], rs = st[24 + b];
    {
        // 16 col-groups of 8 c x 16 rows/pass; 2 batches, 12 nt loads in flight
        const int c8 = (t & 15) * 8, rb = t >> 4;
        const ushort* xb = x1Tb + (size_t)b * DS + (size_t)n0 * 128;
        const uint*  wb = lnwbT + (size_t)n0 * 128;
#pragma unroll
        for (int gb = 0; gb < 2; ++gb) {
            s8b xv[4]; u4v wv0[4], wv1[4];
#pragma unroll
            for (int u = 0; u < 4; ++u) {
                int nn = (gb * 4 + u) * 16 + rb;
                xv[u]  = __builtin_nontemporal_load((const s8b*)(xb + (size_t)nn * 128 + c8));
                wv0[u] = __builtin_nontemporal_load((const u4v*)(wb + (size_t)nn * 128 + c8));
                wv1[u] = __builtin_nontemporal_load((const u4v*)(wb + (size_t)nn * 128 + c8 + 4));
            }
#pragma unroll
            for (int u = 0; u < 4; ++u) {
                int nn = (gb * 4 + u) * 16 + rb;
                ushort4 p0, p1;
                float xe;
                xe = b2f((ushort)xv[u][0]);
                p0.x = f2b(fmaf((xe - mu) * rs, b2f((ushort)(wv0[u].x & 0xffffu)), b2f((ushort)(wv0[u].x >> 16))));
                xe = b2f((ushort)xv[u][1]);
                p0.y = f2b(fmaf((xe - mu) * rs, b2f((ushort)(wv0[u].y & 0xffffu)), b2f((ushort)(wv0[u].y >> 16))));
                xe = b2f((ushort)xv[u][2]);
                p0.z = f2b(fmaf((xe - mu) * rs, b2f((ushort)(wv0[u].z & 0xffffu)), b2f((ushort)(wv0[u].z >> 16))));
                xe = b2f((ushort)xv[u][3]);
                p0.w = f2b(fmaf((xe - mu) * rs, b2f((ushort)(wv0[u].w & 0xffffu)), b2f((ushort)(wv0[u].w >> 16))));
                xe = b2f((ushort)xv[u][4]);
                p1.x = f2b(fmaf((xe - mu) * rs, b2f((ushort)(wv1[u].x & 0xffffu)), b2f((ushort)(wv1[u].x >> 16))));
                xe = b2f((ushort)xv[u][5]);
                p1.y = f2b(fmaf((xe - mu) * rs, b2f((ushort)(wv1[u].y & 0xffffu)), b2f((ushort)(wv1[u].y >> 16))));
                xe = b2f((ushort)xv[u][6]);
                p1.z = f2b(fmaf((xe - mu) * rs, b2f((ushort)(wv1[u].z & 0xffffu)), b2f((ushort)(wv1[u].z >> 16))));
                xe = b2f((ushort)xv[u][7]);
                p1.w = f2b(fmaf((xe - mu) * rs, b2f((ushort)(wv1[u].w & 0xffffu)), b2f((ushort)(wv1[u].w >> 16))));
                *(ushort4*)&xT[swz4(nn, c8)] = p0;
                *(ushort4*)&xT[swz4(nn, c8 + 4)] = p1;
            }
        }
    }
    const int orow = wave * 32 + r;
    // prefetch GEMM1 A-slice for os=0 (8 independent loads), overlaps barrier
    s8b a1[8];
    {
        const ushort* w1p = w1b + (size_t)orow * 128 + q * 8;
#pragma unroll
        for (int m = 0; m < 2; ++m)
#pragma unroll
            for (int kk = 0; kk < 4; ++kk)
                a1[m * 4 + kk] = *(const s8b*)(w1p + m * 16 * 128 + kk * 32);
    }
    __syncthreads();
    // acc2 initialized with b2 (bias folded into MFMA C-in)
    float4 b2q0 = *(const float4*)&b2v[wave * 32 + q * 4];
    float4 b2q1 = *(const float4*)&b2v[wave * 32 + 16 + q * 4];
    f4 acc2[2][8];
#pragma unroll
    for (int j = 0; j < 8; ++j) {
        acc2[0][j] = (f4){b2q0.x, b2q0.y, b2q0.z, b2q0.w};
        acc2[1][j] = (f4){b2q1.x, b2q1.y, b2q1.z, b2q1.w};
    }

    for (int os = 0; os < 4; ++os) {
        // ---- GEMM1: h[os-slice rows owned by wave] = W1 x1 + b1 (b1 in C-in) ----
        float4 b1q0 = *(const float4*)&b1v[os * 128 + wave * 32 + q * 4];
        float4 b1q1 = *(const float4*)&b1v[os * 128 + wave * 32 + 16 + q * 4];
        f4 acc1[2][8];
#pragma unroll
        for (int j = 0; j < 8; ++j) {
            acc1[0][j] = (f4){b1q0.x, b1q0.y, b1q0.z, b1q0.w};
            acc1[1][j] = (f4){b1q1.x, b1q1.y, b1q1.z, b1q1.w};
        }
#pragma unroll
        for (int kk = 0; kk < 4; ++kk) {
            const int c0 = kk * 32 + q * 8;
#pragma unroll
            for (int j = 0; j < 8; ++j) {
                s8b bx = *(const s8b*)&xT[swz8(j * 16 + r, c0)];
                acc1[0][j] = __builtin_amdgcn_mfma_f32_16x16x32_bf16(a1[kk],     bx, acc1[0][j], 0, 0, 0);
                acc1[1][j] = __builtin_amdgcn_mfma_f32_16x16x32_bf16(a1[4 + kk], bx, acc1[1][j], 0, 0, 0);
            }
        }
        // prefetch GEMM2 A-slice for this os (independent of hT)
        s8b a2[8];
        {
            const ushort* w2p = w2b + (size_t)orow * 512 + os * 128 + q * 8;
#pragma unroll
            for (int m = 0; m < 2; ++m)
#pragma unroll
                for (int kk = 0; kk < 4; ++kk)
                    a2[m * 4 + kk] = *(const s8b*)(w2p + m * 16 * 512 + kk * 32);
        }
        // ---- gelu -> hT (cross-wave) ----
#pragma unroll
        for (int m = 0; m < 2; ++m) {
            const int hr0 = wave * 32 + m * 16 + q * 4;
#pragma unroll
            for (int j = 0; j < 8; ++j) {
                ushort4 pk;
                pk.x = f2b(gelu_f(acc1[m][j][0]));
                pk.y = f2b(gelu_f(acc1[m][j][1]));
                pk.z = f2b(gelu_f(acc1[m][j][2]));
                pk.w = f2b(gelu_f(acc1[m][j][3]));
                *(ushort4*)&hT[swz4(j * 16 + r, hr0)] = pk;
            }
        }
        __syncthreads();   // hT complete across waves
        // ---- GEMM2: acc2 += W2[:, os-slice] h ----
#pragma unroll
        for (int kk = 0; kk < 4; ++kk) {
            const int c0 = kk * 32 + q * 8;
#pragma unroll
            for (int j = 0; j < 8; ++j) {
                s8b hx = *(const s8b*)&hT[swz8(j * 16 + r, c0)];
                acc2[0][j] = __builtin_amdgcn_mfma_f32_16x16x32_bf16(a2[kk],     hx, acc2[0][j], 0, 0, 0);
                acc2[1][j] = __builtin_amdgcn_mfma_f32_16x16x32_bf16(a2[4 + kk], hx, acc2[1][j], 0, 0, 0);
            }
        }
        // prefetch next os's GEMM1 A-slice (overlaps barrier drain)
        if (os < 3) {
            const ushort* w1p = w1b + (size_t)((os + 1) * 128 + orow) * 128 + q * 8;
#pragma unroll
            for (int m = 0; m < 2; ++m)
#pragma unroll
                for (int kk = 0; kk < 4; ++kk)
                    a1[m * 4 + kk] = *(const s8b*)(w1p + m * 16 * 128 + kk * 32);
        }
        __syncthreads();   // hT consumed; safe to overwrite next os
    }
    // ---- epilogue: residual (b2 already in acc2), nt strided store, LN2 stats ----
    float s = 0.f, sq = 0.f;
#pragma unroll
    for (int m = 0; m < 2; ++m) {
        const int o0 = wave * 32 + m * 16 + q * 4;
#pragma unroll
        for (int j = 0; j < 8; ++j) {
            const int nn = j * 16 + r;
            ushort4 xr = *(const ushort4*)&xT[swz4(nn, o0)];
            float v0 = acc2[m][j][0] + b2f(xr.x);
            float v1 = acc2[m][j][1] + b2f(xr.y);
            float v2 = acc2[m][j][2] + b2f(xr.z);
            float v3 = acc2[m][j][3] + b2f(xr.w);
            float* op = xout + (size_t)b * DS + n0 + nn;
            __builtin_nontemporal_store(v0, op + (size_t)(o0 + 0) * N_SP);
            __builtin_nontemporal_store(v1, op + (size_t)(o0 + 1) * N_SP);
            __builtin_nontemporal_store(v2, op + (size_t)(o0 + 2) * N_SP);
            __builtin_nontemporal_store(v3, op + (size_t)(o0 + 3) * N_SP);
            s += (v0 + v1) + (v2 + v3);
            sq = fmaf(v0, v0, sq); sq = fmaf(v1, v1, sq);
            sq = fmaf(v2, v2, sq); sq = fmaf(v3, v3, sq);
        }
    }
#pragma unroll
    for (int off = 32; off > 0; off >>= 1) {
        s += __shfl_down(s, off, 64);
        sq += __shfl_down(sq, off, 64);
    }
    if (lane == 0) {
        atomicAdd(&st[32 + b], s);
        atomicAdd(&st[40 + b], sq);
    }
}

extern "C" void kernel_launch(void* const* d_in, const int* in_sizes, int n_in,
                              void* d_out, int out_size, void* d_ws, size_t ws_size,
                              hipStream_t stream) {
    const float* x      = (const float*)d_in[0];
    const float* qkv_w  = (const float*)d_in[1];
    const float* proj_w = (const float*)d_in[2];
    const float* proj_b = (const float*)d_in[3];
    const float* ln1_w  = (const float*)d_in[4];
    const float* ln1_b  = (const float*)d_in[5];
    const float* ln2_w  = (const float*)d_in[6];
    const float* ln2_b  = (const float*)d_in[7];
    const float* mlp_w1 = (const float*)d_in[8];
    const float* mlp_b1 = (const float*)d_in[9];
    const float* mlp_w2 = (const float*)d_in[10];
    const float* mlp_b2 = (const float*)d_in[11];
    float* out = (float*)d_out;

    char* wsb = (char*)d_ws;
    // small persistent region
    float*  st    = (float*)wsb;                      // 256 B
    float*  attn  = (float*)(wsb + 256);              // 65,536
    float*  PT    = (float*)(wsb + 65792);            // 65,536
    ushort* Mbb   = (ushort*)(wsb + 131328);          // 262,144
    ushort* w1b   = (ushort*)(wsb + 393472);          // 131,072
    ushort* w2b   = (ushort*)(wsb + 524544);          // 131,072
    float*  G     = (float*)(wsb + 655616);           // 524,288
    uint*   lnwbT = (uint*)(wsb + 1179904);           // 16,777,216
    // big dual-use region (stream-ordered lifetimes):
    //   Gpart (33.5MB, dead after k_greduce) -> x1Tb bf16 (67MB, dead after
    //   k_mlp) -> lnwb2 (16MB, for k_lnapply)
    float*  Gpart = (float*)(wsb + 18874368);         // 33,554,432
    ushort* x1Tb  = (ushort*)(wsb + 18874368);        // 67,108,864
    uint*   lnwb2 = (uint*)(wsb + 18874368);          // 16,777,216

    hipMemsetAsync(st, 0, 64 * sizeof(float), stream);

    k_transpose<<<64, 256, 0, stream>>>(proj_w, PT, 128, 128);
    k_cvt<<<256, 256, 0, stream>>>(mlp_w1, w1b, 65536);
    k_cvt<<<256, 256, 0, stream>>>(mlp_w2, w2b, 65536);
    k_packln<<<16384, 256, 0, stream>>>(ln1_w, ln1_b, lnwbT);

    k_cov<<<dim3(64, 8), 256, 0, stream>>>(x, Gpart);
    k_greduce<<<512, 256, 0, stream>>>(Gpart, G);
    k_gram_small<<<64, 256, 0, stream>>>(G, qkv_w, attn);
    k_mfold<<<8, 256, 0, stream>>>(attn, qkv_w, PT, Mbb);

    k_attnproj<<<dim3(256, 8), 256, 0, stream>>>(x, Mbb, proj_b, x1Tb, st);
    k_finalize<<<1, 64, 0, stream>>>(st, 0);
    k_mlp<<<dim3(256, 8), 256, 0, stream>>>(x1Tb, out, w1b, mlp_b1, w2b, mlp_b2,
                                            lnwbT, st);
    // x1Tb dead; pack LN2 params into the same region for the final apply
    k_packflat<<<16384, 256, 0, stream>>>(ln2_w, ln2_b, lnwb2);
    k_finalize<<<1, 64, 0, stream>>>(st, 32);
    k_lnapply<<<32768, 256, 0, stream>>>(out, lnwb2, st, 32, out);
}